// Round 6
// baseline (284.245 us; speedup 1.0000x reference)
//
#include <hip/hip_runtime.h>
#include <cstdint>
#include <cstddef>

#define NPTS 4096
#define BATCH 4
#define FEAT 256
#define KNN 32

// ---------------- workspace layout (bytes) ----------------
static constexpr size_t OFF_IDX  = 0;                          // int32 [B*N*K]  = 2 MB
static constexpr size_t OFF_HT   = 2u * 1024 * 1024;           // f32  [B*N*F]  = 16 MB
static constexpr size_t OFF_CNT  = OFF_HT + 16u * 1024 * 1024; // int32 [B*N]   = 64 KB
static constexpr size_t OFF_PART = OFF_CNT + 64u * 1024;       // f32  [64*512] = 128 KB
static constexpr size_t OFF_SC   = OFF_PART + 128u * 1024;     // f32 [256]
static constexpr size_t OFF_SH   = OFF_SC + 4096;              // f32 [256]

template<int CTRL>
static __device__ __forceinline__ uint32_t dpp32(uint32_t x) {
    return (uint32_t)__builtin_amdgcn_update_dpp(-1, (int)x, CTRL, 0xF, 0xF, false);
}

// full-wave u32 min; result returned uniform (from lane 63)
static __device__ __forceinline__ uint32_t wave_min_u32(uint32_t v) {
    v = min(v, dpp32<0x111>(v));  // row_shr:1
    v = min(v, dpp32<0x112>(v));  // row_shr:2
    v = min(v, dpp32<0x114>(v));  // row_shr:4
    v = min(v, dpp32<0x118>(v));  // row_shr:8
    v = min(v, dpp32<0x142>(v));  // row_bcast:15
    v = min(v, dpp32<0x143>(v));  // row_bcast:31
    return (uint32_t)__builtin_amdgcn_readlane((int)v, 63);
}

// ---------------- KNN: one wave per (b, n) row; registers only, no LDS ----------------
// Split sorted top-4 queue per lane: qd (mapped dist, ascending, stable ties) + qi (index).
// Exact (dist, idx) lexicographic selection == reference stable top_k.
__global__ __launch_bounds__(256, 4) void knn_kernel(const float* __restrict__ xyz,
                                                     int* __restrict__ out_idx,
                                                     int* __restrict__ cnt) {
#pragma clang fp contract(off)
    const int lane = threadIdx.x & 63;
    const int n = blockIdx.x * 4 + (threadIdx.x >> 6);
    const int b = blockIdx.y;
    const float* xb = xyz + (size_t)b * 3 * NPTS;
    const float x0n = xb[n];
    const float x1n = xb[NPTS + n];
    const float sqn = x0n * x0n + x1n * x1n;  // round(x0^2)+round(x1^2), no contraction

    // this lane's 64 candidates are contiguous: m = lane*64 + i
    const float* xr0 = xb + lane * 64;
    const float* xr1 = xb + NPTS + lane * 64;
    const uint32_t mbase = (uint32_t)(lane * 64);

    uint32_t qd0 = ~0u, qd1 = ~0u, qd2 = ~0u, qd3 = ~0u;
    uint32_t qi0 = 0, qi1 = 0, qi2 = 0, qi3 = 0;

#pragma unroll
    for (int i0 = 0; i0 < 64; i0 += 4) {
        const float4 a0 = *(const float4*)(xr0 + i0);
        const float4 a1 = *(const float4*)(xr1 + i0);
#define CAND(X0, X1, J)                                                          \
    {                                                                            \
        const float x0m = (X0), x1m = (X1);                                      \
        const float sqm = x0m * x0m + x1m * x1m;                                 \
        const float p = __builtin_fmaf(x1n, x1m, x0n * x0m);                     \
        const float d = (sqm - 2.0f * p) + sqn;                                  \
        uint32_t u = __float_as_uint(d);                                         \
        u ^= (uint32_t)((int32_t)u >> 31) | 0x80000000u;                         \
        const uint32_t mi = mbase + (uint32_t)(i0 + (J));                        \
        const bool c0 = u < qd0, c1 = u < qd1, c2 = u < qd2, c3 = u < qd3;       \
        qd3 = c3 ? (c2 ? qd2 : u) : qd3;  qi3 = c3 ? (c2 ? qi2 : mi) : qi3;      \
        qd2 = c2 ? (c1 ? qd1 : u) : qd2;  qi2 = c2 ? (c1 ? qi1 : mi) : qi2;      \
        qd1 = c1 ? (c0 ? qd0 : u) : qd1;  qi1 = c1 ? (c0 ? qi0 : mi) : qi1;      \
        qd0 = c0 ? u : qd0;               qi0 = c0 ? mi : qi0;                   \
    }
        CAND(a0.x, a1.x, 0)
        CAND(a0.y, a1.y, 1)
        CAND(a0.z, a1.z, 2)
        CAND(a0.w, a1.w, 3)
#undef CAND
    }

    int navail = 4;
    uint32_t widx = 0;  // lane k accumulates winner k
#pragma unroll 1
    for (int k = 0; k < KNN; ++k) {
        // global min dist over per-lane queue heads
        const uint32_t wd = wave_min_u32(qd0);
        // smallest index among heads achieving wd (exact lexicographic tie-break)
        const uint32_t t = (qd0 == wd) ? qi0 : 0xFFFFFFFFu;
        const uint32_t wm = wave_min_u32(t);
        // lane k keeps winner k (wm is wave-uniform)
        widx = (lane == k) ? wm : widx;
        // branchless pop on the owner lane
        const bool pop = (lane == (int)(wm >> 6));
        qd0 = pop ? qd1 : qd0;  qi0 = pop ? qi1 : qi0;
        qd1 = pop ? qd2 : qd1;  qi1 = pop ? qi2 : qi1;
        qd2 = pop ? qd3 : qd2;  qi2 = pop ? qi3 : qi2;
        qd3 = pop ? 0xFFFFFFFFu : qd3;
        navail -= pop ? 1 : 0;
        if (navail == 0) {  // rare (P ~ 1e-4/row): exact refill by recompute
            qd0 = qd1 = qd2 = qd3 = ~0u;
            qi0 = qi1 = qi2 = qi3 = 0;
#pragma unroll 4
            for (int i = 0; i < 64; ++i) {
                const float x0m = xr0[i], x1m = xr1[i];
                const float sqm = x0m * x0m + x1m * x1m;
                const float p = __builtin_fmaf(x1n, x1m, x0n * x0m);
                const float d = (sqm - 2.0f * p) + sqn;
                uint32_t u = __float_as_uint(d);
                u ^= (uint32_t)((int32_t)u >> 31) | 0x80000000u;
                const uint32_t mi = mbase + (uint32_t)i;
                const bool keep = (u > wd) || (u == wd && mi > wm);
                u = keep ? u : 0xFFFFFFFFu;
                const bool c0 = u < qd0, c1 = u < qd1, c2 = u < qd2, c3 = u < qd3;
                qd3 = c3 ? (c2 ? qd2 : u) : qd3;  qi3 = c3 ? (c2 ? qi2 : mi) : qi3;
                qd2 = c2 ? (c1 ? qd1 : u) : qd2;  qi2 = c2 ? (c1 ? qi1 : mi) : qi2;
                qd1 = c1 ? (c0 ? qd0 : u) : qd1;  qi1 = c1 ? (c0 ? qi0 : mi) : qi1;
                qd0 = c0 ? u : qd0;               qi0 = c0 ? mi : qi0;
            }
            navail = 4;
        }
    }
    // batched winner write + fused usage counts (distinct addresses within the wave)
    if (lane < KNN) {
        out_idx[((size_t)b * NPTS + n) * KNN + lane] = (int)widx;
        atomicAdd(&cnt[b * NPTS + (int)widx], 1);
    }
}

// ---------------- H = W @ feat[b] + bias, stored as Ht[b][n][f] ----------------
__global__ __launch_bounds__(256) void gemm_kernel(const float* __restrict__ feat,
                                                   const float* __restrict__ W,
                                                   const float* __restrict__ bias,
                                                   float* __restrict__ Ht) {
    __shared__ float As[64][64];  // [c][n_local]
    __shared__ float Bs[64][65];  // [c][f_local], padded
    const int b = blockIdx.z;
    const int n0 = blockIdx.x * 64;
    const int f0 = blockIdx.y * 64;
    const int t = threadIdx.x;
    const int tn = t % 16, tf = t / 16;
    float acc[4][4] = {};
    const float* fb = feat + (size_t)b * FEAT * NPTS;
    for (int c0 = 0; c0 < FEAT; c0 += 64) {
        for (int e = t; e < 4096; e += 256) {
            const int c = e >> 6, nl = e & 63;
            As[c][nl] = fb[(size_t)(c0 + c) * NPTS + n0 + nl];
        }
        for (int e = t; e < 4096; e += 256) {
            const int fl = e >> 6, c = e & 63;
            Bs[c][fl] = W[(size_t)(f0 + fl) * FEAT + c0 + c];
        }
        __syncthreads();
        for (int c = 0; c < 64; ++c) {
            float a[4], bb[4];
            for (int j = 0; j < 4; ++j) a[j] = As[c][tn * 4 + j];
            for (int i = 0; i < 4; ++i) bb[i] = Bs[c][tf * 4 + i];
            for (int j = 0; j < 4; ++j)
                for (int i = 0; i < 4; ++i)
                    acc[j][i] = __builtin_fmaf(a[j], bb[i], acc[j][i]);
        }
        __syncthreads();
    }
    for (int j = 0; j < 4; ++j) {
        const int n = n0 + tn * 4 + j;
        float4 v;
        v.x = acc[j][0] + bias[f0 + tf * 4 + 0];
        v.y = acc[j][1] + bias[f0 + tf * 4 + 1];
        v.z = acc[j][2] + bias[f0 + tf * 4 + 2];
        v.w = acc[j][3] + bias[f0 + tf * 4 + 3];
        *(float4*)(Ht + ((size_t)b * NPTS + n) * FEAT + f0 + tf * 4) = v;
    }
}

// ---------------- count-weighted per-channel partial sums ----------------
__global__ __launch_bounds__(256) void stats_partial(const float* __restrict__ Ht,
                                                     const int* __restrict__ cnt,
                                                     float* __restrict__ part) {
    const int b = blockIdx.y;
    const int n0 = blockIdx.x * 256;
    const int f = threadIdx.x;
    float s = 0.f, s2 = 0.f;
    for (int nl = 0; nl < 256; ++nl) {
        const int n = n0 + nl;
        const float c = (float)cnt[b * NPTS + n];
        const float v = Ht[((size_t)b * NPTS + n) * FEAT + f];
        s += c * v;
        s2 += c * v * v;
    }
    const int blk = b * 16 + blockIdx.x;
    part[blk * 512 + f] = s;
    part[blk * 512 + 256 + f] = s2;
}

__global__ __launch_bounds__(256) void stats_final(const float* __restrict__ part,
                                                   const float* __restrict__ gamma,
                                                   const float* __restrict__ beta,
                                                   float* __restrict__ sc,
                                                   float* __restrict__ sh) {
    const int f = threadIdx.x;
    float s = 0.f, s2 = 0.f;
    for (int blk = 0; blk < 64; ++blk) {
        s += part[blk * 512 + f];
        s2 += part[blk * 512 + 256 + f];
    }
    const float inv = 1.0f / (float)(BATCH * NPTS * KNN);
    const float mean = s * inv;
    const float var = s2 * inv - mean * mean;
    const float scale = gamma[f] * rsqrtf(var + 1e-5f);
    sc[f] = scale;
    sh[f] = beta[f] - scale * mean;
}

// ---------------- gather + affine + relu + max over K ----------------
// NOTE: the read MUST be ib[k*NPTS + n] — this is the reference's raw
// (F, N*K) -> (F, K, N) view scramble, not a [n][k] row-major access.
#define NT 32
__global__ __launch_bounds__(256) void out_kernel(const float* __restrict__ Ht,
                                                  const int* __restrict__ idx,
                                                  const float* __restrict__ sc,
                                                  const float* __restrict__ sh,
                                                  float* __restrict__ out) {
    __shared__ float tile[NT][FEAT + 1];
    const int b = blockIdx.y;
    const int n0 = blockIdx.x * NT;
    const int f = threadIdx.x;
    const float scale = sc[f];
    const float shift = sh[f];
    const float* Hb = Ht + (size_t)b * NPTS * FEAT;
    const int* ib = idx + (size_t)b * NPTS * KNN;
    for (int nl = 0; nl < NT; ++nl) {
        const int n = n0 + nl;
        float acc = -1e30f;
        for (int k = 0; k < KNN; ++k) {
            const int u = ib[k * NPTS + n];  // uniform across lanes -> scalar load
            const float v = Hb[(size_t)u * FEAT + f];
            acc = fmaxf(acc, __builtin_fmaf(v, scale, shift));
        }
        tile[nl][f] = fmaxf(acc, 0.0f);
    }
    __syncthreads();
    const int nl2 = threadIdx.x & (NT - 1);
    const int fbase = threadIdx.x >> 5;  // 0..7
    for (int ff = 0; ff < FEAT; ff += 8) {
        const int f2 = fbase + ff;
        out[((size_t)b * FEAT + f2) * NPTS + n0 + nl2] = tile[nl2][f2];
    }
}

extern "C" void kernel_launch(void* const* d_in, const int* in_sizes, int n_in,
                              void* d_out, int out_size, void* d_ws, size_t ws_size,
                              hipStream_t stream) {
    (void)in_sizes; (void)n_in; (void)out_size; (void)ws_size;
    const float* xyz   = (const float*)d_in[0];
    const float* feat  = (const float*)d_in[1];
    const float* W     = (const float*)d_in[2];
    const float* bias  = (const float*)d_in[3];
    const float* gamma = (const float*)d_in[4];
    const float* beta  = (const float*)d_in[5];
    float* out = (float*)d_out;
    char* ws = (char*)d_ws;
    int*   idx  = (int*)(ws + OFF_IDX);
    float* Ht   = (float*)(ws + OFF_HT);
    int*   cnt  = (int*)(ws + OFF_CNT);
    float* part = (float*)(ws + OFF_PART);
    float* sc   = (float*)(ws + OFF_SC);
    float* sh   = (float*)(ws + OFF_SH);

    (void)hipMemsetAsync(cnt, 0, BATCH * NPTS * sizeof(int), stream);
    knn_kernel<<<dim3(NPTS / 4, BATCH), 256, 0, stream>>>(xyz, idx, cnt);
    gemm_kernel<<<dim3(NPTS / 64, FEAT / 64, BATCH), 256, 0, stream>>>(feat, W, bias, Ht);
    stats_partial<<<dim3(NPTS / 256, BATCH), 256, 0, stream>>>(Ht, cnt, part);
    stats_final<<<1, 256, 0, stream>>>(part, gamma, beta, sc, sh);
    out_kernel<<<dim3(NPTS / NT, BATCH), 256, 0, stream>>>(Ht, idx, sc, sh, out);
}

// Round 7
// 253.100 us; speedup vs baseline: 1.1231x; 1.1231x over previous
//
#include <hip/hip_runtime.h>
#include <cstdint>
#include <cstddef>

#define NPTS 4096
#define BATCH 4
#define FEAT 256
#define KNN 32

// ---------------- workspace layout (bytes) ----------------
static constexpr size_t OFF_IDX  = 0;                          // int32 [B*N*K]  = 2 MB
static constexpr size_t OFF_HT   = 2u * 1024 * 1024;           // f32  [B*N*F]  = 16 MB
static constexpr size_t OFF_CNT  = OFF_HT + 16u * 1024 * 1024; // int32 [B*N]   = 64 KB
static constexpr size_t OFF_PART = OFF_CNT + 64u * 1024;       // f32  [64*512] = 128 KB
static constexpr size_t OFF_SC   = OFF_PART + 128u * 1024;     // f32 [256]
static constexpr size_t OFF_SH   = OFF_SC + 4096;              // f32 [256]

template<int CTRL>
static __device__ __forceinline__ uint32_t dpp32(uint32_t x) {
    return (uint32_t)__builtin_amdgcn_update_dpp(-1, (int)x, CTRL, 0xF, 0xF, false);
}

// full-wave u32 min; result returned uniform (via lane 63)
static __device__ __forceinline__ uint32_t wave_min_u32(uint32_t v) {
    v = min(v, dpp32<0x111>(v));  // row_shr:1
    v = min(v, dpp32<0x112>(v));  // row_shr:2
    v = min(v, dpp32<0x114>(v));  // row_shr:4
    v = min(v, dpp32<0x118>(v));  // row_shr:8
    v = min(v, dpp32<0x142>(v));  // row_bcast:15
    v = min(v, dpp32<0x143>(v));  // row_bcast:31
    return (uint32_t)__builtin_amdgcn_readlane((int)v, 63);
}

// ---------------- KNN: one wave per (b, n) row; registers only, no LDS ----------------
// Round-3-proven skeleton (partial unroll, per-round lane-0 store+atomic with
// wave-uniform address) + split u32 queues and dual-u32 DPP reduce.
__global__ __launch_bounds__(256, 4) void knn_kernel(const float* __restrict__ xyz,
                                                     int* __restrict__ out_idx,
                                                     int* __restrict__ cnt) {
#pragma clang fp contract(off)
    const int lane = threadIdx.x & 63;
    const int n = blockIdx.x * 4 + (threadIdx.x >> 6);
    const int b = blockIdx.y;
    const float* xb = xyz + (size_t)b * 3 * NPTS;
    const float x0n = xb[n];
    const float x1n = xb[NPTS + n];
    const float sqn = x0n * x0n + x1n * x1n;  // round(x0^2)+round(x1^2), no contraction

    // this lane's 64 candidates are contiguous: m = lane*64 + i
    const float* xr0 = xb + lane * 64;
    const float* xr1 = xb + NPTS + lane * 64;
    const uint32_t mbase = (uint32_t)(lane * 64);

    uint32_t qd0 = ~0u, qd1 = ~0u, qd2 = ~0u, qd3 = ~0u;
    uint32_t qi0 = 0, qi1 = 0, qi2 = 0, qi3 = 0;

#pragma unroll 4
    for (int i0 = 0; i0 < 64; i0 += 4) {
        const float4 a0 = *(const float4*)(xr0 + i0);
        const float4 a1 = *(const float4*)(xr1 + i0);
#define CAND(X0, X1, J)                                                          \
    {                                                                            \
        const float x0m = (X0), x1m = (X1);                                      \
        const float sqm = x0m * x0m + x1m * x1m;                                 \
        const float p = __builtin_fmaf(x1n, x1m, x0n * x0m);                     \
        const float d = (sqm - 2.0f * p) + sqn;                                  \
        uint32_t u = __float_as_uint(d);                                         \
        u ^= (uint32_t)((int32_t)u >> 31) | 0x80000000u;                         \
        const uint32_t mi = mbase + (uint32_t)(i0 + (J));                        \
        const bool c0 = u < qd0, c1 = u < qd1, c2 = u < qd2, c3 = u < qd3;       \
        qd3 = c3 ? (c2 ? qd2 : u) : qd3;  qi3 = c3 ? (c2 ? qi2 : mi) : qi3;      \
        qd2 = c2 ? (c1 ? qd1 : u) : qd2;  qi2 = c2 ? (c1 ? qi1 : mi) : qi2;      \
        qd1 = c1 ? (c0 ? qd0 : u) : qd1;  qi1 = c1 ? (c0 ? qi0 : mi) : qi1;      \
        qd0 = c0 ? u : qd0;               qi0 = c0 ? mi : qi0;                   \
    }
        CAND(a0.x, a1.x, 0)
        CAND(a0.y, a1.y, 1)
        CAND(a0.z, a1.z, 2)
        CAND(a0.w, a1.w, 3)
#undef CAND
    }

    int navail = 4;
    int* myout = out_idx + ((size_t)b * NPTS + n) * KNN;
#pragma unroll 1
    for (int k = 0; k < KNN; ++k) {
        // lexicographic wave min: min dist, then min index among heads at that dist
        const uint32_t wd = wave_min_u32(qd0);
        const uint32_t t = (qd0 == wd) ? qi0 : 0xFFFFFFFFu;
        const uint32_t wm = wave_min_u32(t);
        if (lane == 0) {
            myout[k] = (int)wm;                     // winner index (uniform addr/value)
            atomicAdd(&cnt[b * NPTS + (int)wm], 1); // fused usage count (uniform addr)
        }
        // branchless pop on the owner lane
        const bool pop = (lane == (int)(wm >> 6));
        qd0 = pop ? qd1 : qd0;  qi0 = pop ? qi1 : qi0;
        qd1 = pop ? qd2 : qd1;  qi1 = pop ? qi2 : qi1;
        qd2 = pop ? qd3 : qd2;  qi2 = pop ? qi3 : qi2;
        qd3 = pop ? 0xFFFFFFFFu : qd3;
        navail -= pop ? 1 : 0;
        if (navail == 0) {  // rare: exact refill by recompute
            qd0 = qd1 = qd2 = qd3 = ~0u;
            qi0 = qi1 = qi2 = qi3 = 0;
#pragma unroll 4
            for (int i = 0; i < 64; ++i) {
                const float x0m = xr0[i], x1m = xr1[i];
                const float sqm = x0m * x0m + x1m * x1m;
                const float p = __builtin_fmaf(x1n, x1m, x0n * x0m);
                const float d = (sqm - 2.0f * p) + sqn;
                uint32_t u = __float_as_uint(d);
                u ^= (uint32_t)((int32_t)u >> 31) | 0x80000000u;
                const uint32_t mi = mbase + (uint32_t)i;
                const bool keep = (u > wd) || (u == wd && mi > wm);
                u = keep ? u : 0xFFFFFFFFu;
                const bool c0 = u < qd0, c1 = u < qd1, c2 = u < qd2, c3 = u < qd3;
                qd3 = c3 ? (c2 ? qd2 : u) : qd3;  qi3 = c3 ? (c2 ? qi2 : mi) : qi3;
                qd2 = c2 ? (c1 ? qd1 : u) : qd2;  qi2 = c2 ? (c1 ? qi1 : mi) : qi2;
                qd1 = c1 ? (c0 ? qd0 : u) : qd1;  qi1 = c1 ? (c0 ? qi0 : mi) : qi1;
                qd0 = c0 ? u : qd0;               qi0 = c0 ? mi : qi0;
            }
            navail = 4;
        }
    }
}

// ---------------- H = W @ feat[b] + bias, stored as Ht[b][n][f] ----------------
__global__ __launch_bounds__(256) void gemm_kernel(const float* __restrict__ feat,
                                                   const float* __restrict__ W,
                                                   const float* __restrict__ bias,
                                                   float* __restrict__ Ht) {
    __shared__ float As[64][64];  // [c][n_local]
    __shared__ float Bs[64][65];  // [c][f_local], padded
    const int b = blockIdx.z;
    const int n0 = blockIdx.x * 64;
    const int f0 = blockIdx.y * 64;
    const int t = threadIdx.x;
    const int tn = t % 16, tf = t / 16;
    float acc[4][4] = {};
    const float* fb = feat + (size_t)b * FEAT * NPTS;
    for (int c0 = 0; c0 < FEAT; c0 += 64) {
        for (int e = t; e < 4096; e += 256) {
            const int c = e >> 6, nl = e & 63;
            As[c][nl] = fb[(size_t)(c0 + c) * NPTS + n0 + nl];
        }
        for (int e = t; e < 4096; e += 256) {
            const int fl = e >> 6, c = e & 63;
            Bs[c][fl] = W[(size_t)(f0 + fl) * FEAT + c0 + c];
        }
        __syncthreads();
        for (int c = 0; c < 64; ++c) {
            float a[4], bb[4];
            for (int j = 0; j < 4; ++j) a[j] = As[c][tn * 4 + j];
            for (int i = 0; i < 4; ++i) bb[i] = Bs[c][tf * 4 + i];
            for (int j = 0; j < 4; ++j)
                for (int i = 0; i < 4; ++i)
                    acc[j][i] = __builtin_fmaf(a[j], bb[i], acc[j][i]);
        }
        __syncthreads();
    }
    for (int j = 0; j < 4; ++j) {
        const int n = n0 + tn * 4 + j;
        float4 v;
        v.x = acc[j][0] + bias[f0 + tf * 4 + 0];
        v.y = acc[j][1] + bias[f0 + tf * 4 + 1];
        v.z = acc[j][2] + bias[f0 + tf * 4 + 2];
        v.w = acc[j][3] + bias[f0 + tf * 4 + 3];
        *(float4*)(Ht + ((size_t)b * NPTS + n) * FEAT + f0 + tf * 4) = v;
    }
}

// ---------------- count-weighted per-channel partial sums ----------------
__global__ __launch_bounds__(256) void stats_partial(const float* __restrict__ Ht,
                                                     const int* __restrict__ cnt,
                                                     float* __restrict__ part) {
    const int b = blockIdx.y;
    const int n0 = blockIdx.x * 256;
    const int f = threadIdx.x;
    float s = 0.f, s2 = 0.f;
    for (int nl = 0; nl < 256; ++nl) {
        const int n = n0 + nl;
        const float c = (float)cnt[b * NPTS + n];
        const float v = Ht[((size_t)b * NPTS + n) * FEAT + f];
        s += c * v;
        s2 += c * v * v;
    }
    const int blk = b * 16 + blockIdx.x;
    part[blk * 512 + f] = s;
    part[blk * 512 + 256 + f] = s2;
}

__global__ __launch_bounds__(256) void stats_final(const float* __restrict__ part,
                                                   const float* __restrict__ gamma,
                                                   const float* __restrict__ beta,
                                                   float* __restrict__ sc,
                                                   float* __restrict__ sh) {
    const int f = threadIdx.x;
    float s = 0.f, s2 = 0.f;
    for (int blk = 0; blk < 64; ++blk) {
        s += part[blk * 512 + f];
        s2 += part[blk * 512 + 256 + f];
    }
    const float inv = 1.0f / (float)(BATCH * NPTS * KNN);
    const float mean = s * inv;
    const float var = s2 * inv - mean * mean;
    const float scale = gamma[f] * rsqrtf(var + 1e-5f);
    sc[f] = scale;
    sh[f] = beta[f] - scale * mean;
}

// ---------------- gather + affine + relu + max over K ----------------
// NOTE: the read MUST be ib[k*NPTS + n] — this is the reference's raw
// (F, N*K) -> (F, K, N) view scramble, not a [n][k] row-major access.
#define NT 32
__global__ __launch_bounds__(256) void out_kernel(const float* __restrict__ Ht,
                                                  const int* __restrict__ idx,
                                                  const float* __restrict__ sc,
                                                  const float* __restrict__ sh,
                                                  float* __restrict__ out) {
    __shared__ float tile[NT][FEAT + 1];
    const int b = blockIdx.y;
    const int n0 = blockIdx.x * NT;
    const int f = threadIdx.x;
    const float scale = sc[f];
    const float shift = sh[f];
    const float* Hb = Ht + (size_t)b * NPTS * FEAT;
    const int* ib = idx + (size_t)b * NPTS * KNN;
    for (int nl = 0; nl < NT; ++nl) {
        const int n = n0 + nl;
        float acc = -1e30f;
        for (int k = 0; k < KNN; ++k) {
            const int u = ib[k * NPTS + n];  // uniform across lanes -> scalar load
            const float v = Hb[(size_t)u * FEAT + f];
            acc = fmaxf(acc, __builtin_fmaf(v, scale, shift));
        }
        tile[nl][f] = fmaxf(acc, 0.0f);
    }
    __syncthreads();
    const int nl2 = threadIdx.x & (NT - 1);
    const int fbase = threadIdx.x >> 5;  // 0..7
    for (int ff = 0; ff < FEAT; ff += 8) {
        const int f2 = fbase + ff;
        out[((size_t)b * FEAT + f2) * NPTS + n0 + nl2] = tile[nl2][f2];
    }
}

extern "C" void kernel_launch(void* const* d_in, const int* in_sizes, int n_in,
                              void* d_out, int out_size, void* d_ws, size_t ws_size,
                              hipStream_t stream) {
    (void)in_sizes; (void)n_in; (void)out_size; (void)ws_size;
    const float* xyz   = (const float*)d_in[0];
    const float* feat  = (const float*)d_in[1];
    const float* W     = (const float*)d_in[2];
    const float* bias  = (const float*)d_in[3];
    const float* gamma = (const float*)d_in[4];
    const float* beta  = (const float*)d_in[5];
    float* out = (float*)d_out;
    char* ws = (char*)d_ws;
    int*   idx  = (int*)(ws + OFF_IDX);
    float* Ht   = (float*)(ws + OFF_HT);
    int*   cnt  = (int*)(ws + OFF_CNT);
    float* part = (float*)(ws + OFF_PART);
    float* sc   = (float*)(ws + OFF_SC);
    float* sh   = (float*)(ws + OFF_SH);

    (void)hipMemsetAsync(cnt, 0, BATCH * NPTS * sizeof(int), stream);
    knn_kernel<<<dim3(NPTS / 4, BATCH), 256, 0, stream>>>(xyz, idx, cnt);
    gemm_kernel<<<dim3(NPTS / 64, FEAT / 64, BATCH), 256, 0, stream>>>(feat, W, bias, Ht);
    stats_partial<<<dim3(NPTS / 256, BATCH), 256, 0, stream>>>(Ht, cnt, part);
    stats_final<<<1, 256, 0, stream>>>(part, gamma, beta, sc, sh);
    out_kernel<<<dim3(NPTS / NT, BATCH), 256, 0, stream>>>(Ht, idx, sc, sh, out);
}

// Round 8
// 240.608 us; speedup vs baseline: 1.1814x; 1.0519x over previous
//
#include <hip/hip_runtime.h>
#include <cstdint>
#include <cstddef>

#define NPTS 4096
#define BATCH 4
#define FEAT 256
#define KNN 32

// ---------------- workspace layout (bytes) ----------------
static constexpr size_t OFF_IDX  = 0;                          // int32 [B*N*K]  = 2 MB
static constexpr size_t OFF_HT   = 2u * 1024 * 1024;           // f32  [B*N*F]  = 16 MB
static constexpr size_t OFF_CNT  = OFF_HT + 16u * 1024 * 1024; // int32 [B*N]   = 64 KB
static constexpr size_t OFF_PART = OFF_CNT + 64u * 1024;       // f32  [64*512] = 128 KB
static constexpr size_t OFF_SC   = OFF_PART + 128u * 1024;     // f32 [256]
static constexpr size_t OFF_SH   = OFF_SC + 4096;              // f32 [256]

template<int CTRL>
static __device__ __forceinline__ uint32_t dpp32(uint32_t x) {
    return (uint32_t)__builtin_amdgcn_update_dpp(-1, (int)x, CTRL, 0xF, 0xF, false);
}

// full-wave u32 min; result returned uniform (via lane 63)
static __device__ __forceinline__ uint32_t wave_min_u32(uint32_t v) {
    v = min(v, dpp32<0x111>(v));  // row_shr:1
    v = min(v, dpp32<0x112>(v));  // row_shr:2
    v = min(v, dpp32<0x114>(v));  // row_shr:4
    v = min(v, dpp32<0x118>(v));  // row_shr:8
    v = min(v, dpp32<0x142>(v));  // row_bcast:15
    v = min(v, dpp32<0x143>(v));  // row_bcast:31
    return (uint32_t)__builtin_amdgcn_readlane((int)v, 63);
}

// ---------------- KNN body: one wave per (b, n) row (round-7 code, verbatim) -------
static __device__ __forceinline__ void knn_body(int id, const float* __restrict__ xyz,
                                                int* __restrict__ out_idx,
                                                int* __restrict__ cnt) {
#pragma clang fp contract(off)
    const int lane = threadIdx.x & 63;
    const int b = id >> 10;
    const int n = (id & 1023) * 4 + (threadIdx.x >> 6);
    const float* xb = xyz + (size_t)b * 3 * NPTS;
    const float x0n = xb[n];
    const float x1n = xb[NPTS + n];
    const float sqn = x0n * x0n + x1n * x1n;  // round(x0^2)+round(x1^2), no contraction

    // this lane's 64 candidates are contiguous: m = lane*64 + i
    const float* xr0 = xb + lane * 64;
    const float* xr1 = xb + NPTS + lane * 64;
    const uint32_t mbase = (uint32_t)(lane * 64);

    uint32_t qd0 = ~0u, qd1 = ~0u, qd2 = ~0u, qd3 = ~0u;
    uint32_t qi0 = 0, qi1 = 0, qi2 = 0, qi3 = 0;

#pragma unroll 4
    for (int i0 = 0; i0 < 64; i0 += 4) {
        const float4 a0 = *(const float4*)(xr0 + i0);
        const float4 a1 = *(const float4*)(xr1 + i0);
#define CAND(X0, X1, J)                                                          \
    {                                                                            \
        const float x0m = (X0), x1m = (X1);                                      \
        const float sqm = x0m * x0m + x1m * x1m;                                 \
        const float p = __builtin_fmaf(x1n, x1m, x0n * x0m);                     \
        const float d = (sqm - 2.0f * p) + sqn;                                  \
        uint32_t u = __float_as_uint(d);                                         \
        u ^= (uint32_t)((int32_t)u >> 31) | 0x80000000u;                         \
        const uint32_t mi = mbase + (uint32_t)(i0 + (J));                        \
        const bool c0 = u < qd0, c1 = u < qd1, c2 = u < qd2, c3 = u < qd3;       \
        qd3 = c3 ? (c2 ? qd2 : u) : qd3;  qi3 = c3 ? (c2 ? qi2 : mi) : qi3;      \
        qd2 = c2 ? (c1 ? qd1 : u) : qd2;  qi2 = c2 ? (c1 ? qi1 : mi) : qi2;      \
        qd1 = c1 ? (c0 ? qd0 : u) : qd1;  qi1 = c1 ? (c0 ? qi0 : mi) : qi1;      \
        qd0 = c0 ? u : qd0;               qi0 = c0 ? mi : qi0;                   \
    }
        CAND(a0.x, a1.x, 0)
        CAND(a0.y, a1.y, 1)
        CAND(a0.z, a1.z, 2)
        CAND(a0.w, a1.w, 3)
#undef CAND
    }

    int navail = 4;
    int* myout = out_idx + ((size_t)b * NPTS + n) * KNN;
#pragma unroll 1
    for (int k = 0; k < KNN; ++k) {
        // lexicographic wave min: min dist, then min index among heads at that dist
        const uint32_t wd = wave_min_u32(qd0);
        const uint32_t t = (qd0 == wd) ? qi0 : 0xFFFFFFFFu;
        const uint32_t wm = wave_min_u32(t);
        if (lane == 0) {
            myout[k] = (int)wm;                     // winner index (uniform addr/value)
            atomicAdd(&cnt[b * NPTS + (int)wm], 1); // fused usage count (uniform addr)
        }
        // branchless pop on the owner lane
        const bool pop = (lane == (int)(wm >> 6));
        qd0 = pop ? qd1 : qd0;  qi0 = pop ? qi1 : qi0;
        qd1 = pop ? qd2 : qd1;  qi1 = pop ? qi2 : qi1;
        qd2 = pop ? qd3 : qd2;  qi2 = pop ? qi3 : qi2;
        qd3 = pop ? 0xFFFFFFFFu : qd3;
        navail -= pop ? 1 : 0;
        if (navail == 0) {  // rare: exact refill by recompute
            qd0 = qd1 = qd2 = qd3 = ~0u;
            qi0 = qi1 = qi2 = qi3 = 0;
#pragma unroll 4
            for (int i = 0; i < 64; ++i) {
                const float x0m = xr0[i], x1m = xr1[i];
                const float sqm = x0m * x0m + x1m * x1m;
                const float p = __builtin_fmaf(x1n, x1m, x0n * x0m);
                const float d = (sqm - 2.0f * p) + sqn;
                uint32_t u = __float_as_uint(d);
                u ^= (uint32_t)((int32_t)u >> 31) | 0x80000000u;
                const uint32_t mi = mbase + (uint32_t)i;
                const bool keep = (u > wd) || (u == wd && mi > wm);
                u = keep ? u : 0xFFFFFFFFu;
                const bool c0 = u < qd0, c1 = u < qd1, c2 = u < qd2, c3 = u < qd3;
                qd3 = c3 ? (c2 ? qd2 : u) : qd3;  qi3 = c3 ? (c2 ? qi2 : mi) : qi3;
                qd2 = c2 ? (c1 ? qd1 : u) : qd2;  qi2 = c2 ? (c1 ? qi1 : mi) : qi2;
                qd1 = c1 ? (c0 ? qd0 : u) : qd1;  qi1 = c1 ? (c0 ? qi0 : mi) : qi1;
                qd0 = c0 ? u : qd0;               qi0 = c0 ? mi : qi0;
            }
            navail = 4;
        }
    }
}

// ---------------- fused: knn blocks (4/5) + gemm blocks (1/5), co-resident --------
__global__ __launch_bounds__(256, 4) void fused_knn_gemm(const float* __restrict__ xyz,
                                                         int* __restrict__ out_idx,
                                                         int* __restrict__ cnt,
                                                         const float* __restrict__ feat,
                                                         const float* __restrict__ W,
                                                         const float* __restrict__ bias,
                                                         float* __restrict__ Ht) {
    const int bid = blockIdx.x;
    const int g5 = bid / 5, r5 = bid % 5;
    if (r5 < 4) {
        knn_body(g5 * 4 + r5, xyz, out_idx, cnt);
        return;
    }
    // ---- gemm body (round-7 code, remapped block id) ----
    __shared__ float As[64][64];  // [c][n_local]
    __shared__ float Bs[64][65];  // [c][f_local], padded
    const int q = g5;             // [0, 1024)
    const int b = q >> 8;
    const int rr = q & 255;
    const int n0 = (rr >> 2) * 64;
    const int f0 = (rr & 3) * 64;
    const int t = threadIdx.x;
    const int tn = t % 16, tf = t / 16;
    float acc[4][4] = {};
    const float* fb = feat + (size_t)b * FEAT * NPTS;
    for (int c0 = 0; c0 < FEAT; c0 += 64) {
        for (int e = t; e < 4096; e += 256) {
            const int c = e >> 6, nl = e & 63;
            As[c][nl] = fb[(size_t)(c0 + c) * NPTS + n0 + nl];
        }
        for (int e = t; e < 4096; e += 256) {
            const int fl = e >> 6, c = e & 63;
            Bs[c][fl] = W[(size_t)(f0 + fl) * FEAT + c0 + c];
        }
        __syncthreads();
        for (int c = 0; c < 64; ++c) {
            float a[4], bb[4];
            for (int j = 0; j < 4; ++j) a[j] = As[c][tn * 4 + j];
            for (int i = 0; i < 4; ++i) bb[i] = Bs[c][tf * 4 + i];
            for (int j = 0; j < 4; ++j)
                for (int i = 0; i < 4; ++i)
                    acc[j][i] = __builtin_fmaf(a[j], bb[i], acc[j][i]);
        }
        __syncthreads();
    }
    for (int j = 0; j < 4; ++j) {
        const int n = n0 + tn * 4 + j;
        float4 v;
        v.x = acc[j][0] + bias[f0 + tf * 4 + 0];
        v.y = acc[j][1] + bias[f0 + tf * 4 + 1];
        v.z = acc[j][2] + bias[f0 + tf * 4 + 2];
        v.w = acc[j][3] + bias[f0 + tf * 4 + 3];
        *(float4*)(Ht + ((size_t)b * NPTS + n) * FEAT + f0 + tf * 4) = v;
    }
}

// ---------------- count-weighted per-channel partial sums ----------------
__global__ __launch_bounds__(256) void stats_partial(const float* __restrict__ Ht,
                                                     const int* __restrict__ cnt,
                                                     float* __restrict__ part) {
    const int b = blockIdx.y;
    const int n0 = blockIdx.x * 256;
    const int f = threadIdx.x;
    float s = 0.f, s2 = 0.f;
    for (int nl = 0; nl < 256; ++nl) {
        const int n = n0 + nl;
        const float c = (float)cnt[b * NPTS + n];
        const float v = Ht[((size_t)b * NPTS + n) * FEAT + f];
        s += c * v;
        s2 += c * v * v;
    }
    const int blk = b * 16 + blockIdx.x;
    part[blk * 512 + f] = s;
    part[blk * 512 + 256 + f] = s2;
}

__global__ __launch_bounds__(256) void stats_final(const float* __restrict__ part,
                                                   const float* __restrict__ gamma,
                                                   const float* __restrict__ beta,
                                                   float* __restrict__ sc,
                                                   float* __restrict__ sh) {
    const int f = threadIdx.x;
    float s = 0.f, s2 = 0.f;
    for (int blk = 0; blk < 64; ++blk) {
        s += part[blk * 512 + f];
        s2 += part[blk * 512 + 256 + f];
    }
    const float inv = 1.0f / (float)(BATCH * NPTS * KNN);
    const float mean = s * inv;
    const float var = s2 * inv - mean * mean;
    const float scale = gamma[f] * rsqrtf(var + 1e-5f);
    sc[f] = scale;
    sh[f] = beta[f] - scale * mean;
}

// ---------------- gather + affine + relu + max over K ----------------
// NOTE: the read MUST be ib[k*NPTS + n] — this is the reference's raw
// (F, N*K) -> (F, K, N) view scramble, not a [n][k] row-major access.
#define NT 32
__global__ __launch_bounds__(256) void out_kernel(const float* __restrict__ Ht,
                                                  const int* __restrict__ idx,
                                                  const float* __restrict__ sc,
                                                  const float* __restrict__ sh,
                                                  float* __restrict__ out) {
    __shared__ float tile[NT][FEAT + 1];
    const int b = blockIdx.y;
    const int n0 = blockIdx.x * NT;
    const int f = threadIdx.x;
    const float scale = sc[f];
    const float shift = sh[f];
    const float* Hb = Ht + (size_t)b * NPTS * FEAT;
    const int* ib = idx + (size_t)b * NPTS * KNN;
    for (int nl = 0; nl < NT; ++nl) {
        const int n = n0 + nl;
        float acc = -1e30f;
        for (int k = 0; k < KNN; ++k) {
            const int u = ib[k * NPTS + n];  // uniform across lanes -> scalar load
            const float v = Hb[(size_t)u * FEAT + f];
            acc = fmaxf(acc, __builtin_fmaf(v, scale, shift));
        }
        tile[nl][f] = fmaxf(acc, 0.0f);
    }
    __syncthreads();
    const int nl2 = threadIdx.x & (NT - 1);
    const int fbase = threadIdx.x >> 5;  // 0..7
    for (int ff = 0; ff < FEAT; ff += 8) {
        const int f2 = fbase + ff;
        out[((size_t)b * FEAT + f2) * NPTS + n0 + nl2] = tile[nl2][f2];
    }
}

extern "C" void kernel_launch(void* const* d_in, const int* in_sizes, int n_in,
                              void* d_out, int out_size, void* d_ws, size_t ws_size,
                              hipStream_t stream) {
    (void)in_sizes; (void)n_in; (void)out_size; (void)ws_size;
    const float* xyz   = (const float*)d_in[0];
    const float* feat  = (const float*)d_in[1];
    const float* W     = (const float*)d_in[2];
    const float* bias  = (const float*)d_in[3];
    const float* gamma = (const float*)d_in[4];
    const float* beta  = (const float*)d_in[5];
    float* out = (float*)d_out;
    char* ws = (char*)d_ws;
    int*   idx  = (int*)(ws + OFF_IDX);
    float* Ht   = (float*)(ws + OFF_HT);
    int*   cnt  = (int*)(ws + OFF_CNT);
    float* part = (float*)(ws + OFF_PART);
    float* sc   = (float*)(ws + OFF_SC);
    float* sh   = (float*)(ws + OFF_SH);

    (void)hipMemsetAsync(cnt, 0, BATCH * NPTS * sizeof(int), stream);
    fused_knn_gemm<<<dim3(5120), 256, 0, stream>>>(xyz, idx, cnt, feat, W, bias, Ht);
    stats_partial<<<dim3(NPTS / 256, BATCH), 256, 0, stream>>>(Ht, cnt, part);
    stats_final<<<1, 256, 0, stream>>>(part, gamma, beta, sc, sh);
    out_kernel<<<dim3(NPTS / NT, BATCH), 256, 0, stream>>>(Ht, idx, sc, sh, out);
}